// Round 1
// baseline (1003.000 us; speedup 1.0000x reference)
//
#include <hip/hip_runtime.h>

// Problem: mean over axis 1 of mailbox[50000][32][128] f32 -> out[50000][128] f32.
// Pure streaming reduction: 819.2 MB in, 25.6 MB out, no reuse -> HBM-bound.
// One thread per output float4 (FEAT/4 = 32 per node). Per d-iteration a wave's
// 64 lanes read two contiguous 512B segments (2 nodes x 32 float4) -> coalesced.

constexpr int N_NODES = 50000;
constexpr int MAX_DEG = 32;
constexpr int FEAT    = 128;
constexpr int F4      = FEAT / 4;              // 32 float4 per row
constexpr int TOTAL4  = N_NODES * F4;          // 1.6M output float4

__global__ __launch_bounds__(256) void mean_agg_kernel(
    const float4* __restrict__ in, float4* __restrict__ out) {
    int idx = blockIdx.x * blockDim.x + threadIdx.x;
    if (idx >= TOTAL4) return;
    int n = idx >> 5;          // node index       (idx / F4)
    int j = idx & (F4 - 1);    // float4 within row (idx % F4)
    const float4* p = in + (size_t)n * MAX_DEG * F4 + j;
    float4 acc = make_float4(0.f, 0.f, 0.f, 0.f);
#pragma unroll
    for (int d = 0; d < MAX_DEG; ++d) {
        float4 v = p[(size_t)d * F4];
        acc.x += v.x; acc.y += v.y; acc.z += v.z; acc.w += v.w;
    }
    const float s = 1.0f / MAX_DEG;
    acc.x *= s; acc.y *= s; acc.z *= s; acc.w *= s;
    out[idx] = acc;
}

extern "C" void kernel_launch(void* const* d_in, const int* in_sizes, int n_in,
                              void* d_out, int out_size, void* d_ws, size_t ws_size,
                              hipStream_t stream) {
    const float4* in = (const float4*)d_in[0];
    float4* out = (float4*)d_out;
    const int block = 256;
    const int grid = (TOTAL4 + block - 1) / block;   // 6250 blocks
    mean_agg_kernel<<<grid, block, 0, stream>>>(in, out);
}